// Round 12
// baseline (327.756 us; speedup 1.0000x reference)
//
#include <hip/hip_runtime.h>
#include <math.h>

// Problem constants (fixed by the reference)
#define NND 50000   // nodes
#define LNP 50048   // padded rows: 782 * 64, guard-free gemm
#define NED 600000  // edges
#define CD  128     // channels (in = hid = 128)
#define NG  64      // graphs
#define NBLK 196    // ceil(NND/256) scan blocks
#define GROWS 64    // rows per fused block

typedef short s8v  __attribute__((ext_vector_type(8)));   // 8 bf16 (raw bits) = 4 VGPRs
typedef float f4v  __attribute__((ext_vector_type(4)));   // MFMA accumulator
typedef float f2v  __attribute__((ext_vector_type(2)));
typedef unsigned short u16x4 __attribute__((ext_vector_type(4)));
typedef unsigned short u16x8 __attribute__((ext_vector_type(8)));

static __device__ __forceinline__ unsigned short f2bf(float f) {
  union { float f; unsigned u; } v; v.f = f;
  unsigned r = v.u + 0x7fffu + ((v.u >> 16) & 1u);   // round-to-nearest-even
  return (unsigned short)(r >> 16);
}
static __device__ __forceinline__ float bf2f(unsigned short h) {
  union { unsigned u; float f; } v; v.u = ((unsigned)h) << 16; return v.f;
}
// 4 floats -> 4 packed OCP e4m3 bytes (HW RNE+sat)
static __device__ __forceinline__ unsigned f2fp8x4(float a, float b, float c, float d) {
  int r = __builtin_amdgcn_cvt_pk_fp8_f32(a, b, 0, false);
  r = __builtin_amdgcn_cvt_pk_fp8_f32(c, d, r, true);
  return (unsigned)r;
}
// async global->LDS, 16B per lane (m97 pattern: wave-uniform LDS base + lane*16)
static __device__ __forceinline__ void g2lds(const unsigned short* g, unsigned short* l) {
  __builtin_amdgcn_global_load_lds(
      (const __attribute__((address_space(1))) unsigned*)g,
      (__attribute__((address_space(3))) unsigned*)l, 16, 0, 0);
}

// ---- 3-stage grid scan of cnt[NND] -> offs (exclusive), cur, offs[NND]=total ----
__global__ __launch_bounds__(256) void bsum_k(const int* __restrict__ cnt,
                                              int* __restrict__ bsum) {
  __shared__ int s[256];
  int i = blockIdx.x * 256 + threadIdx.x;
  s[threadIdx.x] = (i < NND) ? cnt[i] : 0;
  __syncthreads();
  for (int off = 128; off > 0; off >>= 1) {
    if (threadIdx.x < off) s[threadIdx.x] += s[threadIdx.x + off];
    __syncthreads();
  }
  if (threadIdx.x == 0) bsum[blockIdx.x] = s[0];
}

// also folds in graph-boundary binary search (batch is SORTED): gb[g]=lower_bound(g)
__global__ __launch_bounds__(256) void bscan_k(const int* __restrict__ bsum,
                                               int* __restrict__ boff,
                                               int* __restrict__ offs,
                                               const int* __restrict__ batch,
                                               int* __restrict__ gb) {
  __shared__ int s[256];
  int t = threadIdx.x;
  if (t <= NG) {
    int lo = 0, hi = NND;
    while (lo < hi) {
      int mid = (lo + hi) >> 1;
      if (batch[mid] < t) lo = mid + 1; else hi = mid;
    }
    gb[t] = lo;
  }
  s[t] = (t < NBLK) ? bsum[t] : 0;
  __syncthreads();
  for (int off = 1; off < 256; off <<= 1) {   // inclusive Hillis-Steele
    int v = (t >= off) ? s[t - off] : 0;
    __syncthreads();
    s[t] += v;
    __syncthreads();
  }
  if (t < NBLK) boff[t] = (t == 0) ? 0 : s[t - 1];
  if (t == NBLK - 1) offs[NND] = s[t];        // grand total
}

__global__ __launch_bounds__(256) void escan_k(const int* __restrict__ cnt,
                                               const int* __restrict__ boff,
                                               int* __restrict__ offs,
                                               int* __restrict__ cur) {
  __shared__ int s[256];
  int i = blockIdx.x * 256 + threadIdx.x;
  int t = threadIdx.x;
  int v = (i < NND) ? cnt[i] : 0;
  s[t] = v;
  __syncthreads();
  for (int off = 1; off < 256; off <<= 1) {   // inclusive Hillis-Steele
    int u = (t >= off) ? s[t - off] : 0;
    __syncthreads();
    s[t] += u;
    __syncthreads();
  }
  if (i < NND) {
    int excl = s[t] - v + boff[blockIdx.x];   // inclusive - self = exclusive
    offs[i] = excl;
    cur[i]  = excl;
  }
}

// ---- CSR fill: csr[pos] = src for edges grouped by dst ----
__global__ void fill_k(const int* __restrict__ src, const int* __restrict__ dst,
                       int* __restrict__ cur, int* __restrict__ csr) {
  int e = blockIdx.x * blockDim.x + threadIdx.x;
  if (e >= NED) return;
  int d = dst[e];
  int pos = atomicAdd(&cur[d], 1);
  csr[pos] = src[e];
}

// ---- merged preamble: x->bf16+fp8 (range 0), weight transposes (range 1),
//      degree count for CSR (range 2, atomics hidden under streaming) ----
struct WPtrs { const float* w[8]; unsigned short* wt[8]; };
__global__ void prep_k(const float* __restrict__ x, unsigned short* __restrict__ xb,
                       unsigned* __restrict__ x8, WPtrs p,
                       const int* __restrict__ dst, int* __restrict__ cnt) {
  int t = blockIdx.x * blockDim.x + threadIdx.x;
  if (t < NND * 32) {                 // one float4 chunk per thread
    float4 v = reinterpret_cast<const float4*>(x)[t];
    u16x4 o;
    o.x = f2bf(v.x); o.y = f2bf(v.y); o.z = f2bf(v.z); o.w = f2bf(v.w);
    reinterpret_cast<u16x4*>(xb)[t] = o;
    x8[t] = f2fp8x4(v.x, v.y, v.z, v.w);
  } else {
    int u = t - NND * 32;             // 8*16384 weight elements
    if (u < 8 * CD * CD) {
      int m = u >> 14, r = u & (CD * CD - 1);
      int n = r >> 7, k = r & 127;
      p.wt[m][r] = f2bf(p.w[m][k * CD + n]);
    } else {
      int e = u - 8 * CD * CD;        // NED degree counts
      if (e < NED) atomicAdd(&cnt[dst[e]], 1);
    }
  }
}

// ---- FUSED SAGE layer v2: fp8 CSR gather-mean -> LDS, then MFMA.
// Per block: 64 rows, 256 threads.
//  - xbuf: root bf16 features via global_load_lds width=16 (fire-and-forget DMA)
//  - B frags (Wl+Wr, all K) register-resident (64 VGPR)
//  - gather: 16 teams x 16 lanes; team handles 4 rows sequentially; lane owns
//    8 channels = one 8B uint2/edge (fp8 row = 128B = 1 line); 8-deep unroll;
//    fp32 accumulate via HW packed fp8->f32; bf16 mean -> abuf (LDS)
//  - one barrier (drains DMA + gather writes), then gemm3's MFMA phase.
// MFMA 16x16x32 bf16; A: m=lane&15,k=quad*8+j; B from WT[n][k]: n=lane&15;
// C/D: col=lane&15, row=quad*4+r (m89/m91-verified).
__global__ __launch_bounds__(256, 4) void sage_k(
    const unsigned* __restrict__ xq, const unsigned short* __restrict__ xb,
    const int* __restrict__ csr, const int* __restrict__ offs,
    const unsigned short* __restrict__ WlT, const unsigned short* __restrict__ WrT,
    const float* __restrict__ bias, unsigned short* __restrict__ hb,
    unsigned char* __restrict__ h8) {
  __shared__ unsigned short abuf[GROWS * CD];   // 16 KB aggregated means
  __shared__ unsigned short xbuf[GROWS * CD];   // 16 KB root features (DMA)

  const int tid  = threadIdx.x;
  const int wave = tid >> 6;
  const int lane = tid & 63;
  const int quad = lane >> 4;
  const int l16  = lane & 15;
  const size_t rbase = (size_t)blockIdx.x * GROWS;

  // xbuf DMA first (fire-and-forget)
#pragma unroll
  for (int j = 0; j < 4; ++j) {
    const int s = j * 256 + tid;            // 16B slot: row = s/16, chunk = s%16
    g2lds(xb + (rbase + (s >> 4)) * CD + (s & 15) * 8, &xbuf[(size_t)s * 8]);
  }

  // B fragments -> registers (overlaps DMA; weights are L2-hot)
  s8v bL[2][4], bR[2][4];
#pragma unroll
  for (int nt = 0; nt < 2; ++nt) {
    const int n = wave * 32 + nt * 16 + l16;
#pragma unroll
    for (int kk = 0; kk < 4; ++kk) {
      size_t woff = (size_t)n * CD + kk * 32 + quad * 8;
      bL[nt][kk] = *reinterpret_cast<const s8v*>(WlT + woff);
      bR[nt][kk] = *reinterpret_cast<const s8v*>(WrT + woff);
    }
  }
  const float bv0 = bias[wave * 32 + l16];
  const float bv1 = bias[wave * 32 + 16 + l16];

  // Gather phase: team handles rows rbase + team*4 + i
  const int team = tid >> 4;
  const int tl   = tid & 15;
  const unsigned* base = xq + tl * 2;            // 2 u32 = 8 fp8 channels
  for (int i = 0; i < 4; ++i) {
    const int rl = team * 4 + i;
    const size_t row = rbase + rl;
    u16x8 o = {};
    if (row < NND) {
      const int e0 = offs[row], e1 = offs[row + 1];
      f2v a01 = {0.f, 0.f}, a23 = {0.f, 0.f}, a45 = {0.f, 0.f}, a67 = {0.f, 0.f};
      int e = e0;
      for (; e + 8 <= e1; e += 8) {
        int s[8];
#pragma unroll
        for (int j = 0; j < 8; ++j) s[j] = csr[e + j];
        uint2 v[8];
#pragma unroll
        for (int j = 0; j < 8; ++j)
          v[j] = *reinterpret_cast<const uint2*>(base + (size_t)s[j] * 32);
#pragma unroll
        for (int j = 0; j < 8; ++j) {
          a01 += __builtin_amdgcn_cvt_pk_f32_fp8(v[j].x, false);
          a23 += __builtin_amdgcn_cvt_pk_f32_fp8(v[j].x, true);
          a45 += __builtin_amdgcn_cvt_pk_f32_fp8(v[j].y, false);
          a67 += __builtin_amdgcn_cvt_pk_f32_fp8(v[j].y, true);
        }
      }
      for (; e + 4 <= e1; e += 4) {
        int s[4];
#pragma unroll
        for (int j = 0; j < 4; ++j) s[j] = csr[e + j];
        uint2 v[4];
#pragma unroll
        for (int j = 0; j < 4; ++j)
          v[j] = *reinterpret_cast<const uint2*>(base + (size_t)s[j] * 32);
#pragma unroll
        for (int j = 0; j < 4; ++j) {
          a01 += __builtin_amdgcn_cvt_pk_f32_fp8(v[j].x, false);
          a23 += __builtin_amdgcn_cvt_pk_f32_fp8(v[j].x, true);
          a45 += __builtin_amdgcn_cvt_pk_f32_fp8(v[j].y, false);
          a67 += __builtin_amdgcn_cvt_pk_f32_fp8(v[j].y, true);
        }
      }
      for (; e < e1; ++e) {
        uint2 v = *reinterpret_cast<const uint2*>(base + (size_t)csr[e] * 32);
        a01 += __builtin_amdgcn_cvt_pk_f32_fp8(v.x, false);
        a23 += __builtin_amdgcn_cvt_pk_f32_fp8(v.x, true);
        a45 += __builtin_amdgcn_cvt_pk_f32_fp8(v.y, false);
        a67 += __builtin_amdgcn_cvt_pk_f32_fp8(v.y, true);
      }
      const float invd = 1.0f / fmaxf((float)(e1 - e0), 1.0f);
      o[0] = f2bf(a01.x * invd); o[1] = f2bf(a01.y * invd);
      o[2] = f2bf(a23.x * invd); o[3] = f2bf(a23.y * invd);
      o[4] = f2bf(a45.x * invd); o[5] = f2bf(a45.y * invd);
      o[6] = f2bf(a67.x * invd); o[7] = f2bf(a67.y * invd);
    }
    *reinterpret_cast<u16x8*>(abuf + rl * CD + tl * 8) = o;
  }

  __syncthreads();   // drains DMA (vmcnt) + LDS writes + barrier

  // MFMA phase (gemm3 structure)
#pragma unroll
  for (int rt = 0; rt < GROWS / 16; ++rt) {
    const unsigned short* arow = abuf + (rt * 16 + l16) * CD + quad * 8;
    const unsigned short* xrow = xbuf + (rt * 16 + l16) * CD + quad * 8;
    f4v acc0 = {}, acc1 = {};
#pragma unroll
    for (int kk = 0; kk < 4; ++kk) {
      s8v aA = *reinterpret_cast<const s8v*>(arow + kk * 32);   // ds_read_b128
      s8v aX = *reinterpret_cast<const s8v*>(xrow + kk * 32);
      acc0 = __builtin_amdgcn_mfma_f32_16x16x32_bf16(aA, bL[0][kk], acc0, 0, 0, 0);
      acc0 = __builtin_amdgcn_mfma_f32_16x16x32_bf16(aX, bR[0][kk], acc0, 0, 0, 0);
      acc1 = __builtin_amdgcn_mfma_f32_16x16x32_bf16(aA, bL[1][kk], acc1, 0, 0, 0);
      acc1 = __builtin_amdgcn_mfma_f32_16x16x32_bf16(aX, bR[1][kk], acc1, 0, 0, 0);
    }
    const size_t row0 = rbase + rt * 16 + quad * 4;
    const int c0 = wave * 32 + l16;
#pragma unroll
    for (int r = 0; r < 4; ++r) {
      const size_t row = row0 + r;
      float v0 = fmaxf(acc0[r] + bv0, 0.0f);
      float v1 = fmaxf(acc1[r] + bv1, 0.0f);
      hb[row * CD + c0]      = f2bf(v0);
      hb[row * CD + c0 + 16] = f2bf(v1);
      if (h8) {
        int p0 = __builtin_amdgcn_cvt_pk_fp8_f32(v0, v0, 0, false);
        int p1 = __builtin_amdgcn_cvt_pk_fp8_f32(v1, v1, 0, false);
        h8[row * CD + c0]      = (unsigned char)p0;
        h8[row * CD + c0 + 16] = (unsigned char)p1;
      }
    }
  }
}

// ---- mean-pool over bf16 features: 32-row chunks, one thread per channel,
// boundary-flush atomics; batch is SORTED. ----
__global__ __launch_bounds__(128) void pool3_k(const unsigned short* __restrict__ h,
                                               const int* __restrict__ batch,
                                               float* __restrict__ pooled) {
  const int c  = threadIdx.x;
  const int r0 = blockIdx.x * 32;
  const int rend = (r0 + 32 < NND) ? r0 + 32 : NND;
  const int g0 = batch[r0];
  const int g1 = batch[rend - 1];
  if (g0 == g1) {
    float acc = 0.f;
#pragma unroll
    for (int i = 0; i < 32; ++i) {
      int row = r0 + i;
      if (row < rend) acc += bf2f(h[(size_t)row * CD + c]);
    }
    atomicAdd(&pooled[g0 * CD + c], acc);
  } else {
    float acc = 0.f;
    int gcur = g0;
    for (int row = r0; row < rend; ++row) {
      int g = batch[row];
      if (g != gcur) {
        atomicAdd(&pooled[gcur * CD + c], acc);
        acc = 0.f; gcur = g;
      }
      acc += bf2f(h[(size_t)row * CD + c]);
    }
    atomicAdd(&pooled[gcur * CD + c], acc);
  }
}

// ---- classifier: out[g] = sigmoid(dot(pooled[g]/cnt, Wc) + bc) ----
__global__ void final_k(const float* __restrict__ pooled, const int* __restrict__ gb,
                        const float* __restrict__ Wc, const float* __restrict__ bc,
                        float* __restrict__ out) {
  int g = blockIdx.x;
  int lane = threadIdx.x;
  float part = pooled[g * CD + lane] * Wc[lane] +
               pooled[g * CD + 64 + lane] * Wc[64 + lane];
#pragma unroll
  for (int off = 32; off > 0; off >>= 1) part += __shfl_down(part, off, 64);
  if (lane == 0) {
    float cnt = (float)(gb[g + 1] - gb[g]);
    float z = part / fmaxf(cnt, 1.0f) + bc[0];
    out[g] = 1.0f / (1.0f + expf(-z));
  }
}

extern "C" void kernel_launch(void* const* d_in, const int* in_sizes, int n_in,
                              void* d_out, int out_size, void* d_ws, size_t ws_size,
                              hipStream_t stream) {
  const float* x   = (const float*)d_in[0];
  const int*   ei  = (const int*)d_in[1];
  const int*   src = ei;             // edge_index[0]
  const int*   dst = ei + NED;       // edge_index[1]
  // d_in[2] = edge_weight: unused by the reference
  const int*   batch = (const int*)d_in[3];
  const float* Wc = (const float*)d_in[16];
  const float* bc = (const float*)d_in[17];
  float* out = (float*)d_out;

  char* w = (char*)d_ws;
  auto alloc = [&](size_t bytes) {
    char* p = w; w += (bytes + 255) & ~(size_t)255; return p;
  };
  // cnti + pooled first and contiguous: one memset covers both
  int* cnti = (int*)alloc(NND * 4);
  float* pooled = (float*)alloc(NG * CD * 4);
  size_t zspan = (size_t)(w - (char*)cnti);
  int* offs = (int*)alloc((NND + 1) * 4);
  int* cur  = (int*)alloc(NND * 4);
  int* csr  = (int*)alloc((size_t)NED * 4);
  int* gb   = (int*)alloc((NG + 1) * 4);
  int* bsum = (int*)alloc(256 * 4);
  int* boff = (int*)alloc(256 * 4);
  unsigned short* xb0 = (unsigned short*)alloc((size_t)LNP * CD * 2);
  unsigned short* xb1 = (unsigned short*)alloc((size_t)LNP * CD * 2);
  unsigned char* x8a = (unsigned char*)alloc((size_t)LNP * CD);
  unsigned char* x8b = (unsigned char*)alloc((size_t)LNP * CD);
  WPtrs wp;
  for (int i = 0; i < 4; ++i) {
    wp.w[2 * i]     = (const float*)d_in[4 + 3 * i];      // Wl{i+1}
    wp.w[2 * i + 1] = (const float*)d_in[5 + 3 * i];      // Wr{i+1}
  }
  for (int i = 0; i < 8; ++i) wp.wt[i] = (unsigned short*)alloc(CD * CD * 2);
  const float* bs[4] = {(const float*)d_in[6],  (const float*)d_in[9],
                        (const float*)d_in[12], (const float*)d_in[15]};

  hipMemsetAsync(cnti, 0, zspan, stream);

  // preamble: converts + weight transposes + degree count in ONE kernel
  prep_k<<<(NND * 32 + 8 * CD * CD + NED + 255) / 256, 256, 0, stream>>>(
      x, xb0, (unsigned*)x8a, wp, dst, cnti);

  // CSR build (per call; inputs are restored before every timed launch)
  bsum_k<<<NBLK, 256, 0, stream>>>(cnti, bsum);
  bscan_k<<<1, 256, 0, stream>>>(bsum, boff, offs, batch, gb);
  escan_k<<<NBLK, 256, 0, stream>>>(cnti, boff, offs, cur);
  fill_k<<<(NED + 255) / 256, 256, 0, stream>>>(src, dst, cur, csr);

  unsigned short* xcur = xb0;
  unsigned short* xnxt = xb1;
  unsigned char* qcur = x8a;
  unsigned char* qnxt = x8b;
  const int ggrid = LNP / GROWS;   // 782, guard-free
  for (int l = 0; l < 4; ++l) {
    sage_k<<<ggrid, 256, 0, stream>>>((const unsigned*)qcur, xcur, csr, offs,
                                      wp.wt[2 * l], wp.wt[2 * l + 1], bs[l],
                                      xnxt, (l < 3) ? qnxt : nullptr);
    unsigned short* t = xcur; xcur = xnxt; xnxt = t;
    unsigned char* q = qcur; qcur = qnxt; qnxt = q;
  }

  pool3_k<<<(NND + 31) / 32, 128, 0, stream>>>(xcur, batch, pooled);
  final_k<<<NG, 64, 0, stream>>>(pooled, gb, Wc, bc, out);
}

// Round 13
// 308.247 us; speedup vs baseline: 1.0633x; 1.0633x over previous
//
#include <hip/hip_runtime.h>
#include <math.h>

// Problem constants (fixed by the reference)
#define NND 50000   // nodes
#define LNP 50048   // padded rows: 782 * 64, guard-free gemm
#define NED 600000  // edges
#define CD  128     // channels (in = hid = 128)
#define NG  64      // graphs
#define NBLK 196    // ceil(NND/256) scan blocks
#define GROWS 64    // rows per fused block

typedef short s8v  __attribute__((ext_vector_type(8)));   // 8 bf16 (raw bits) = 4 VGPRs
typedef float f4v  __attribute__((ext_vector_type(4)));   // MFMA accumulator
typedef float f2v  __attribute__((ext_vector_type(2)));
typedef unsigned short u16x4 __attribute__((ext_vector_type(4)));
typedef unsigned short u16x8 __attribute__((ext_vector_type(8)));

static __device__ __forceinline__ unsigned short f2bf(float f) {
  union { float f; unsigned u; } v; v.f = f;
  unsigned r = v.u + 0x7fffu + ((v.u >> 16) & 1u);   // round-to-nearest-even
  return (unsigned short)(r >> 16);
}
static __device__ __forceinline__ float bf2f(unsigned short h) {
  union { unsigned u; float f; } v; v.u = ((unsigned)h) << 16; return v.f;
}
// 4 floats -> 4 packed OCP e4m3 bytes (HW RNE+sat)
static __device__ __forceinline__ unsigned f2fp8x4(float a, float b, float c, float d) {
  int r = __builtin_amdgcn_cvt_pk_fp8_f32(a, b, 0, false);
  r = __builtin_amdgcn_cvt_pk_fp8_f32(c, d, r, true);
  return (unsigned)r;
}
// async global->LDS, 16B per lane (m97 pattern: wave-uniform LDS base + lane*16)
static __device__ __forceinline__ void g2lds(const unsigned short* g, unsigned short* l) {
  __builtin_amdgcn_global_load_lds(
      (const __attribute__((address_space(1))) unsigned*)g,
      (__attribute__((address_space(3))) unsigned*)l, 16, 0, 0);
}

// ---- 3-stage grid scan of cnt[NND] -> offs (exclusive), cur, offs[NND]=total ----
__global__ __launch_bounds__(256) void bsum_k(const int* __restrict__ cnt,
                                              int* __restrict__ bsum) {
  __shared__ int s[256];
  int i = blockIdx.x * 256 + threadIdx.x;
  s[threadIdx.x] = (i < NND) ? cnt[i] : 0;
  __syncthreads();
  for (int off = 128; off > 0; off >>= 1) {
    if (threadIdx.x < off) s[threadIdx.x] += s[threadIdx.x + off];
    __syncthreads();
  }
  if (threadIdx.x == 0) bsum[blockIdx.x] = s[0];
}

// also folds in graph-boundary binary search (batch is SORTED): gb[g]=lower_bound(g)
__global__ __launch_bounds__(256) void bscan_k(const int* __restrict__ bsum,
                                               int* __restrict__ boff,
                                               int* __restrict__ offs,
                                               const int* __restrict__ batch,
                                               int* __restrict__ gb) {
  __shared__ int s[256];
  int t = threadIdx.x;
  if (t <= NG) {
    int lo = 0, hi = NND;
    while (lo < hi) {
      int mid = (lo + hi) >> 1;
      if (batch[mid] < t) lo = mid + 1; else hi = mid;
    }
    gb[t] = lo;
  }
  s[t] = (t < NBLK) ? bsum[t] : 0;
  __syncthreads();
  for (int off = 1; off < 256; off <<= 1) {   // inclusive Hillis-Steele
    int v = (t >= off) ? s[t - off] : 0;
    __syncthreads();
    s[t] += v;
    __syncthreads();
  }
  if (t < NBLK) boff[t] = (t == 0) ? 0 : s[t - 1];
  if (t == NBLK - 1) offs[NND] = s[t];        // grand total
}

__global__ __launch_bounds__(256) void escan_k(const int* __restrict__ cnt,
                                               const int* __restrict__ boff,
                                               int* __restrict__ offs,
                                               int* __restrict__ cur) {
  __shared__ int s[256];
  int i = blockIdx.x * 256 + threadIdx.x;
  int t = threadIdx.x;
  int v = (i < NND) ? cnt[i] : 0;
  s[t] = v;
  __syncthreads();
  for (int off = 1; off < 256; off <<= 1) {   // inclusive Hillis-Steele
    int u = (t >= off) ? s[t - off] : 0;
    __syncthreads();
    s[t] += u;
    __syncthreads();
  }
  if (i < NND) {
    int excl = s[t] - v + boff[blockIdx.x];   // inclusive - self = exclusive
    offs[i] = excl;
    cur[i]  = excl;
  }
}

// ---- CSR fill: csr[pos] = src for edges grouped by dst ----
__global__ void fill_k(const int* __restrict__ src, const int* __restrict__ dst,
                       int* __restrict__ cur, int* __restrict__ csr) {
  int e = blockIdx.x * blockDim.x + threadIdx.x;
  if (e >= NED) return;
  int d = dst[e];
  int pos = atomicAdd(&cur[d], 1);
  csr[pos] = src[e];
}

// ---- merged preamble: x->bf16+fp8 (range 0), weight transposes (range 1),
//      degree count for CSR (range 2, atomics hidden under streaming) ----
struct WPtrs { const float* w[8]; unsigned short* wt[8]; };
__global__ void prep_k(const float* __restrict__ x, unsigned short* __restrict__ xb,
                       unsigned* __restrict__ x8, WPtrs p,
                       const int* __restrict__ dst, int* __restrict__ cnt) {
  int t = blockIdx.x * blockDim.x + threadIdx.x;
  if (t < NND * 32) {                 // one float4 chunk per thread
    float4 v = reinterpret_cast<const float4*>(x)[t];
    u16x4 o;
    o.x = f2bf(v.x); o.y = f2bf(v.y); o.z = f2bf(v.z); o.w = f2bf(v.w);
    reinterpret_cast<u16x4*>(xb)[t] = o;
    x8[t] = f2fp8x4(v.x, v.y, v.z, v.w);
  } else {
    int u = t - NND * 32;             // 8*16384 weight elements
    if (u < 8 * CD * CD) {
      int m = u >> 14, r = u & (CD * CD - 1);
      int n = r >> 7, k = r & 127;
      p.wt[m][r] = f2bf(p.w[m][k * CD + n]);
    } else {
      int e = u - 8 * CD * CD;        // NED degree counts
      if (e < NED) atomicAdd(&cnt[dst[e]], 1);
    }
  }
}

// ---- FUSED SAGE layer v3: fp8 CSR gather-mean -> LDS, MFMA, optional fused pool.
// Per block: 64 rows, 256 threads.
//  - xbuf: root bf16 features via global_load_lds width=16 (fire-and-forget DMA)
//  - B frags (Wl+Wr, all K) register-resident (64 VGPR)
//  - gather: 32 teams x 8 lanes; team handles 2 rows; lane owns 16 channels =
//    one 16B uint4/edge (fp8 row = 128B = 1 line, 8 lines in flight per
//    wave-instr); 4-deep unroll; fp32 accumulate via HW packed fp8->f32;
//    bf16 mean -> abuf (LDS)
//  - one barrier, then MFMA phase (ds_read_b128).
//  - pooled != nullptr (last layer): NO global feature write; column-reduce
//    via shfl_xor butterfly (fast path: block within one graph) or per-row
//    atomics (boundary/tail blocks), into pooled[g*CD+c].
// MFMA 16x16x32 bf16; A: m=lane&15,k=quad*8+j; B from WT[n][k]: n=lane&15;
// C/D: col=lane&15, row=quad*4+r (m89/m91-verified).
__global__ __launch_bounds__(256, 4) void sage_k(
    const unsigned* __restrict__ xq, const unsigned short* __restrict__ xb,
    const int* __restrict__ csr, const int* __restrict__ offs,
    const unsigned short* __restrict__ WlT, const unsigned short* __restrict__ WrT,
    const float* __restrict__ bias, unsigned short* __restrict__ hb,
    unsigned char* __restrict__ h8, const int* __restrict__ batch,
    float* __restrict__ pooled) {
  __shared__ unsigned short abuf[GROWS * CD];   // 16 KB aggregated means
  __shared__ unsigned short xbuf[GROWS * CD];   // 16 KB root features (DMA)
  __shared__ int sB[GROWS];                     // graph ids of the block's rows

  const int tid  = threadIdx.x;
  const int wave = tid >> 6;
  const int lane = tid & 63;
  const int quad = lane >> 4;
  const int l16  = lane & 15;
  const size_t rbase = (size_t)blockIdx.x * GROWS;

  // xbuf DMA first (fire-and-forget)
#pragma unroll
  for (int j = 0; j < 4; ++j) {
    const int s = j * 256 + tid;            // 16B slot: row = s/16, chunk = s%16
    g2lds(xb + (rbase + (s >> 4)) * CD + (s & 15) * 8, &xbuf[(size_t)s * 8]);
  }

  // batch ids for pooling (tiny)
  if (pooled && tid < GROWS) {
    size_t row = rbase + tid;
    sB[tid] = (row < NND) ? batch[row] : -1;
  }

  // B fragments -> registers (overlaps DMA; weights are L2-hot)
  s8v bL[2][4], bR[2][4];
#pragma unroll
  for (int nt = 0; nt < 2; ++nt) {
    const int n = wave * 32 + nt * 16 + l16;
#pragma unroll
    for (int kk = 0; kk < 4; ++kk) {
      size_t woff = (size_t)n * CD + kk * 32 + quad * 8;
      bL[nt][kk] = *reinterpret_cast<const s8v*>(WlT + woff);
      bR[nt][kk] = *reinterpret_cast<const s8v*>(WrT + woff);
    }
  }
  const float bv0 = bias[wave * 32 + l16];
  const float bv1 = bias[wave * 32 + 16 + l16];

  // Gather phase: 32 teams x 8 lanes; team handles rows rbase + team*2 + i
  {
    const int team = tid >> 3;
    const int tl   = tid & 7;                  // owns channels [tl*16, tl*16+16)
    const unsigned* base = xq + tl * 4;        // 4 u32 = 16 fp8 channels
    for (int i = 0; i < 2; ++i) {
      const int rl = team * 2 + i;
      const size_t row = rbase + rl;
      u16x8 o0 = {}, o1 = {};
      if (row < NND) {
        const int e0 = offs[row], e1 = offs[row + 1];
        f2v a[8] = {};
        int e = e0;
        for (; e + 4 <= e1; e += 4) {
          int s[4];
#pragma unroll
          for (int j = 0; j < 4; ++j) s[j] = csr[e + j];
          uint4 v[4];
#pragma unroll
          for (int j = 0; j < 4; ++j)
            v[j] = *reinterpret_cast<const uint4*>(base + (size_t)s[j] * 32);
#pragma unroll
          for (int j = 0; j < 4; ++j) {
            a[0] += __builtin_amdgcn_cvt_pk_f32_fp8(v[j].x, false);
            a[1] += __builtin_amdgcn_cvt_pk_f32_fp8(v[j].x, true);
            a[2] += __builtin_amdgcn_cvt_pk_f32_fp8(v[j].y, false);
            a[3] += __builtin_amdgcn_cvt_pk_f32_fp8(v[j].y, true);
            a[4] += __builtin_amdgcn_cvt_pk_f32_fp8(v[j].z, false);
            a[5] += __builtin_amdgcn_cvt_pk_f32_fp8(v[j].z, true);
            a[6] += __builtin_amdgcn_cvt_pk_f32_fp8(v[j].w, false);
            a[7] += __builtin_amdgcn_cvt_pk_f32_fp8(v[j].w, true);
          }
        }
        for (; e < e1; ++e) {
          uint4 v = *reinterpret_cast<const uint4*>(base + (size_t)csr[e] * 32);
          a[0] += __builtin_amdgcn_cvt_pk_f32_fp8(v.x, false);
          a[1] += __builtin_amdgcn_cvt_pk_f32_fp8(v.x, true);
          a[2] += __builtin_amdgcn_cvt_pk_f32_fp8(v.y, false);
          a[3] += __builtin_amdgcn_cvt_pk_f32_fp8(v.y, true);
          a[4] += __builtin_amdgcn_cvt_pk_f32_fp8(v.z, false);
          a[5] += __builtin_amdgcn_cvt_pk_f32_fp8(v.z, true);
          a[6] += __builtin_amdgcn_cvt_pk_f32_fp8(v.w, false);
          a[7] += __builtin_amdgcn_cvt_pk_f32_fp8(v.w, true);
        }
        const float invd = 1.0f / fmaxf((float)(e1 - e0), 1.0f);
#pragma unroll
        for (int c = 0; c < 4; ++c) {
          o0[2 * c]     = f2bf(a[c].x * invd);
          o0[2 * c + 1] = f2bf(a[c].y * invd);
          o1[2 * c]     = f2bf(a[4 + c].x * invd);
          o1[2 * c + 1] = f2bf(a[4 + c].y * invd);
        }
      }
      *reinterpret_cast<u16x8*>(abuf + rl * CD + tl * 16)     = o0;
      *reinterpret_cast<u16x8*>(abuf + rl * CD + tl * 16 + 8) = o1;
    }
  }

  __syncthreads();   // drains DMA (vmcnt) + LDS writes + barrier

  const bool fast = pooled && (rbase + GROWS <= NND) && (sB[0] == sB[GROWS - 1]);
  const int c0 = wave * 32 + l16;
  float p0 = 0.f, p1 = 0.f;

  // MFMA phase
#pragma unroll
  for (int rt = 0; rt < GROWS / 16; ++rt) {
    const unsigned short* arow = abuf + (rt * 16 + l16) * CD + quad * 8;
    const unsigned short* xrow = xbuf + (rt * 16 + l16) * CD + quad * 8;
    f4v acc0 = {}, acc1 = {};
#pragma unroll
    for (int kk = 0; kk < 4; ++kk) {
      s8v aA = *reinterpret_cast<const s8v*>(arow + kk * 32);   // ds_read_b128
      s8v aX = *reinterpret_cast<const s8v*>(xrow + kk * 32);
      acc0 = __builtin_amdgcn_mfma_f32_16x16x32_bf16(aA, bL[0][kk], acc0, 0, 0, 0);
      acc0 = __builtin_amdgcn_mfma_f32_16x16x32_bf16(aX, bR[0][kk], acc0, 0, 0, 0);
      acc1 = __builtin_amdgcn_mfma_f32_16x16x32_bf16(aA, bL[1][kk], acc1, 0, 0, 0);
      acc1 = __builtin_amdgcn_mfma_f32_16x16x32_bf16(aX, bR[1][kk], acc1, 0, 0, 0);
    }
    const size_t row0 = rbase + rt * 16 + quad * 4;
#pragma unroll
    for (int r = 0; r < 4; ++r) {
      const size_t row = row0 + r;
      float v0 = fmaxf(acc0[r] + bv0, 0.0f);
      float v1 = fmaxf(acc1[r] + bv1, 0.0f);
      if (hb) {
        hb[row * CD + c0]      = f2bf(v0);
        hb[row * CD + c0 + 16] = f2bf(v1);
      }
      if (h8) {
        int q0 = __builtin_amdgcn_cvt_pk_fp8_f32(v0, v0, 0, false);
        int q1 = __builtin_amdgcn_cvt_pk_fp8_f32(v1, v1, 0, false);
        h8[row * CD + c0]      = (unsigned char)q0;
        h8[row * CD + c0 + 16] = (unsigned char)q1;
      }
      if (pooled) {
        if (fast) {
          p0 += v0; p1 += v1;
        } else {
          int g = sB[rt * 16 + quad * 4 + r];
          if (g >= 0) {
            atomicAdd(&pooled[g * CD + c0], v0);
            atomicAdd(&pooled[g * CD + c0 + 16], v1);
          }
        }
      }
    }
  }

  if (fast) {   // butterfly column-reduce across quads, one atomic pair per col
    p0 += __shfl_xor(p0, 16, 64);
    p0 += __shfl_xor(p0, 32, 64);
    p1 += __shfl_xor(p1, 16, 64);
    p1 += __shfl_xor(p1, 32, 64);
    if (quad == 0) {
      const int g = sB[0];
      atomicAdd(&pooled[g * CD + c0], p0);
      atomicAdd(&pooled[g * CD + c0 + 16], p1);
    }
  }
}

// ---- classifier: out[g] = sigmoid(dot(pooled[g]/cnt, Wc) + bc) ----
__global__ void final_k(const float* __restrict__ pooled, const int* __restrict__ gb,
                        const float* __restrict__ Wc, const float* __restrict__ bc,
                        float* __restrict__ out) {
  int g = blockIdx.x;
  int lane = threadIdx.x;
  float part = pooled[g * CD + lane] * Wc[lane] +
               pooled[g * CD + 64 + lane] * Wc[64 + lane];
#pragma unroll
  for (int off = 32; off > 0; off >>= 1) part += __shfl_down(part, off, 64);
  if (lane == 0) {
    float cnt = (float)(gb[g + 1] - gb[g]);
    float z = part / fmaxf(cnt, 1.0f) + bc[0];
    out[g] = 1.0f / (1.0f + expf(-z));
  }
}

extern "C" void kernel_launch(void* const* d_in, const int* in_sizes, int n_in,
                              void* d_out, int out_size, void* d_ws, size_t ws_size,
                              hipStream_t stream) {
  const float* x   = (const float*)d_in[0];
  const int*   ei  = (const int*)d_in[1];
  const int*   src = ei;             // edge_index[0]
  const int*   dst = ei + NED;       // edge_index[1]
  // d_in[2] = edge_weight: unused by the reference
  const int*   batch = (const int*)d_in[3];
  const float* Wc = (const float*)d_in[16];
  const float* bc = (const float*)d_in[17];
  float* out = (float*)d_out;

  char* w = (char*)d_ws;
  auto alloc = [&](size_t bytes) {
    char* p = w; w += (bytes + 255) & ~(size_t)255; return p;
  };
  // cnti + pooled first and contiguous: one memset covers both
  int* cnti = (int*)alloc(NND * 4);
  float* pooled = (float*)alloc(NG * CD * 4);
  size_t zspan = (size_t)(w - (char*)cnti);
  int* offs = (int*)alloc((NND + 1) * 4);
  int* cur  = (int*)alloc(NND * 4);
  int* csr  = (int*)alloc((size_t)NED * 4);
  int* gb   = (int*)alloc((NG + 1) * 4);
  int* bsum = (int*)alloc(256 * 4);
  int* boff = (int*)alloc(256 * 4);
  unsigned short* xb0 = (unsigned short*)alloc((size_t)LNP * CD * 2);
  unsigned short* xb1 = (unsigned short*)alloc((size_t)LNP * CD * 2);
  unsigned char* x8a = (unsigned char*)alloc((size_t)LNP * CD);
  unsigned char* x8b = (unsigned char*)alloc((size_t)LNP * CD);
  WPtrs wp;
  for (int i = 0; i < 4; ++i) {
    wp.w[2 * i]     = (const float*)d_in[4 + 3 * i];      // Wl{i+1}
    wp.w[2 * i + 1] = (const float*)d_in[5 + 3 * i];      // Wr{i+1}
  }
  for (int i = 0; i < 8; ++i) wp.wt[i] = (unsigned short*)alloc(CD * CD * 2);
  const float* bs[4] = {(const float*)d_in[6],  (const float*)d_in[9],
                        (const float*)d_in[12], (const float*)d_in[15]};

  hipMemsetAsync(cnti, 0, zspan, stream);

  // preamble: converts + weight transposes + degree count in ONE kernel
  prep_k<<<(NND * 32 + 8 * CD * CD + NED + 255) / 256, 256, 0, stream>>>(
      x, xb0, (unsigned*)x8a, wp, dst, cnti);

  // CSR build (per call; inputs are restored before every timed launch)
  bsum_k<<<NBLK, 256, 0, stream>>>(cnti, bsum);
  bscan_k<<<1, 256, 0, stream>>>(bsum, boff, offs, batch, gb);
  escan_k<<<NBLK, 256, 0, stream>>>(cnti, boff, offs, cur);
  fill_k<<<(NED + 255) / 256, 256, 0, stream>>>(src, dst, cur, csr);

  unsigned short* xcur = xb0;
  unsigned short* xnxt = xb1;
  unsigned char* qcur = x8a;
  unsigned char* qnxt = x8b;
  const int ggrid = LNP / GROWS;   // 782, guard-free
  for (int l = 0; l < 4; ++l) {
    if (l < 3) {
      sage_k<<<ggrid, 256, 0, stream>>>((const unsigned*)qcur, xcur, csr, offs,
                                        wp.wt[2 * l], wp.wt[2 * l + 1], bs[l],
                                        xnxt, qnxt, batch, nullptr);
      unsigned short* t = xcur; xcur = xnxt; xnxt = t;
      unsigned char* q = qcur; qcur = qnxt; qnxt = q;
    } else {
      // last layer: no feature output at all — pooling fused into epilogue
      sage_k<<<ggrid, 256, 0, stream>>>((const unsigned*)qcur, xcur, csr, offs,
                                        wp.wt[2 * l], wp.wt[2 * l + 1], bs[l],
                                        nullptr, nullptr, batch, pooled);
    }
  }

  final_k<<<NG, 64, 0, stream>>>(pooled, gb, Wc, bc, out);
}

// Round 14
// 307.148 us; speedup vs baseline: 1.0671x; 1.0036x over previous
//
#include <hip/hip_runtime.h>
#include <math.h>

// Problem constants (fixed by the reference)
#define NND 50000   // nodes
#define LNP 50048   // padded rows: 782 * 64, guard-free gemm
#define NED 600000  // edges
#define CD  128     // channels (in = hid = 128)
#define NG  64      // graphs
#define NBLK 196    // ceil(NND/256) scan blocks
#define GROWS 64    // rows per fused block

typedef short s8v  __attribute__((ext_vector_type(8)));   // 8 bf16 (raw bits) = 4 VGPRs
typedef float f4v  __attribute__((ext_vector_type(4)));   // MFMA accumulator
typedef float f2v  __attribute__((ext_vector_type(2)));
typedef unsigned short u16x4 __attribute__((ext_vector_type(4)));
typedef unsigned short u16x8 __attribute__((ext_vector_type(8)));

static __device__ __forceinline__ unsigned short f2bf(float f) {
  union { float f; unsigned u; } v; v.f = f;
  unsigned r = v.u + 0x7fffu + ((v.u >> 16) & 1u);   // round-to-nearest-even
  return (unsigned short)(r >> 16);
}
// truncating f32->bf16: EXACT when the value is fp8-representable (mantissa fits)
static __device__ __forceinline__ unsigned short f2bf_t(float f) {
  union { float f; unsigned u; } v; v.f = f;
  return (unsigned short)(v.u >> 16);
}
// 4 floats -> 4 packed OCP e4m3 bytes (HW RNE+sat)
static __device__ __forceinline__ unsigned f2fp8x4(float a, float b, float c, float d) {
  int r = __builtin_amdgcn_cvt_pk_fp8_f32(a, b, 0, false);
  r = __builtin_amdgcn_cvt_pk_fp8_f32(c, d, r, true);
  return (unsigned)r;
}
// 8 packed fp8 bytes -> 8 bf16 (exact: e4m3 subset of bf16)
static __device__ __forceinline__ s8v fp8x8_to_bf16(uint2 v) {
  f2v c0 = __builtin_amdgcn_cvt_pk_f32_fp8(v.x, false);
  f2v c1 = __builtin_amdgcn_cvt_pk_f32_fp8(v.x, true);
  f2v c2 = __builtin_amdgcn_cvt_pk_f32_fp8(v.y, false);
  f2v c3 = __builtin_amdgcn_cvt_pk_f32_fp8(v.y, true);
  union { u16x8 u; s8v s; } o;
  o.u[0] = f2bf_t(c0.x); o.u[1] = f2bf_t(c0.y);
  o.u[2] = f2bf_t(c1.x); o.u[3] = f2bf_t(c1.y);
  o.u[4] = f2bf_t(c2.x); o.u[5] = f2bf_t(c2.y);
  o.u[6] = f2bf_t(c3.x); o.u[7] = f2bf_t(c3.y);
  return o.s;
}
// async global->LDS, 16B per lane (m97 pattern: wave-uniform LDS base + lane*16)
static __device__ __forceinline__ void g2lds8(const unsigned char* g, unsigned char* l) {
  __builtin_amdgcn_global_load_lds(
      (const __attribute__((address_space(1))) unsigned*)g,
      (__attribute__((address_space(3))) unsigned*)l, 16, 0, 0);
}

// ---- 3-stage grid scan of cnt[NND] -> offs (exclusive), cur, offs[NND]=total ----
__global__ __launch_bounds__(256) void bsum_k(const int* __restrict__ cnt,
                                              int* __restrict__ bsum) {
  __shared__ int s[256];
  int i = blockIdx.x * 256 + threadIdx.x;
  s[threadIdx.x] = (i < NND) ? cnt[i] : 0;
  __syncthreads();
  for (int off = 128; off > 0; off >>= 1) {
    if (threadIdx.x < off) s[threadIdx.x] += s[threadIdx.x + off];
    __syncthreads();
  }
  if (threadIdx.x == 0) bsum[blockIdx.x] = s[0];
}

// also folds in graph-boundary binary search (batch is SORTED): gb[g]=lower_bound(g)
__global__ __launch_bounds__(256) void bscan_k(const int* __restrict__ bsum,
                                               int* __restrict__ boff,
                                               int* __restrict__ offs,
                                               const int* __restrict__ batch,
                                               int* __restrict__ gb) {
  __shared__ int s[256];
  int t = threadIdx.x;
  if (t <= NG) {
    int lo = 0, hi = NND;
    while (lo < hi) {
      int mid = (lo + hi) >> 1;
      if (batch[mid] < t) lo = mid + 1; else hi = mid;
    }
    gb[t] = lo;
  }
  s[t] = (t < NBLK) ? bsum[t] : 0;
  __syncthreads();
  for (int off = 1; off < 256; off <<= 1) {   // inclusive Hillis-Steele
    int v = (t >= off) ? s[t - off] : 0;
    __syncthreads();
    s[t] += v;
    __syncthreads();
  }
  if (t < NBLK) boff[t] = (t == 0) ? 0 : s[t - 1];
  if (t == NBLK - 1) offs[NND] = s[t];        // grand total
}

__global__ __launch_bounds__(256) void escan_k(const int* __restrict__ cnt,
                                               const int* __restrict__ boff,
                                               int* __restrict__ offs,
                                               int* __restrict__ cur) {
  __shared__ int s[256];
  int i = blockIdx.x * 256 + threadIdx.x;
  int t = threadIdx.x;
  int v = (i < NND) ? cnt[i] : 0;
  s[t] = v;
  __syncthreads();
  for (int off = 1; off < 256; off <<= 1) {   // inclusive Hillis-Steele
    int u = (t >= off) ? s[t - off] : 0;
    __syncthreads();
    s[t] += u;
    __syncthreads();
  }
  if (i < NND) {
    int excl = s[t] - v + boff[blockIdx.x];   // inclusive - self = exclusive
    offs[i] = excl;
    cur[i]  = excl;
  }
}

// ---- CSR fill: csr[pos] = src for edges grouped by dst ----
__global__ void fill_k(const int* __restrict__ src, const int* __restrict__ dst,
                       int* __restrict__ cur, int* __restrict__ csr) {
  int e = blockIdx.x * blockDim.x + threadIdx.x;
  if (e >= NED) return;
  int d = dst[e];
  int pos = atomicAdd(&cur[d], 1);
  csr[pos] = src[e];
}

// ---- merged preamble: x->fp8 (range 0), weight transposes (range 1),
//      degree count for CSR (range 2, atomics hidden under streaming) ----
struct WPtrs { const float* w[8]; unsigned short* wt[8]; };
__global__ void prep_k(const float* __restrict__ x, unsigned* __restrict__ x8,
                       WPtrs p, const int* __restrict__ dst, int* __restrict__ cnt) {
  int t = blockIdx.x * blockDim.x + threadIdx.x;
  if (t < NND * 32) {                 // one float4 chunk per thread
    float4 v = reinterpret_cast<const float4*>(x)[t];
    x8[t] = f2fp8x4(v.x, v.y, v.z, v.w);
  } else {
    int u = t - NND * 32;             // 8*16384 weight elements
    if (u < 8 * CD * CD) {
      int m = u >> 14, r = u & (CD * CD - 1);
      int n = r >> 7, k = r & 127;
      p.wt[m][r] = f2bf(p.w[m][k * CD + n]);
    } else {
      int e = u - 8 * CD * CD;        // NED degree counts
      if (e < NED) atomicAdd(&cnt[dst[e]], 1);
    }
  }
}

// ---- FUSED SAGE layer v4 (fp8-only feature state):
// Per block: 64 rows, 256 threads. Feature tables are fp8 e4m3 (128B rows).
//  - x8buf: root fp8 rows via global_load_lds width=16 (8 KB, fire-and-forget)
//  - B frags (Wl+Wr bf16, all K) register-resident (64 VGPR)
//  - gather: 32 teams x 8 lanes; team handles 2 rows; lane owns 16 channels =
//    one 16B uint4/edge; 4-deep unroll; fp32 accumulate via packed fp8->f32;
//    bf16 mean -> abuf (LDS, 16 KB)
//  - one barrier, then MFMA: A_agg = ds_read_b128 bf16; A_root = ds_read 8B
//    fp8 + exact convert to bf16 (fp8 values are bf16-representable).
//  - layers 0-2: write ONLY the fp8 next-layer table (6.4 MB). Layer 3
//    (pooled != nullptr): no feature output; column-reduce via shfl_xor
//    butterfly (block within one graph) or per-row atomics (boundary blocks).
// MFMA 16x16x32 bf16; A: m=lane&15,k=quad*8+j; B from WT[n][k]: n=lane&15;
// C/D: col=lane&15, row=quad*4+r (m89/m91-verified).
__global__ __launch_bounds__(256, 4) void sage_k(
    const unsigned* __restrict__ xq,
    const int* __restrict__ csr, const int* __restrict__ offs,
    const unsigned short* __restrict__ WlT, const unsigned short* __restrict__ WrT,
    const float* __restrict__ bias, unsigned char* __restrict__ h8,
    const int* __restrict__ batch, float* __restrict__ pooled) {
  __shared__ unsigned short abuf[GROWS * CD];   // 16 KB aggregated means (bf16)
  __shared__ unsigned char  x8buf[GROWS * CD];  // 8 KB root features (fp8 DMA)
  __shared__ int sB[GROWS];                     // graph ids of the block's rows

  const int tid  = threadIdx.x;
  const int wave = tid >> 6;
  const int lane = tid & 63;
  const int quad = lane >> 4;
  const int l16  = lane & 15;
  const size_t rbase = (size_t)blockIdx.x * GROWS;

  // root fp8 DMA first (fire-and-forget): 512 slots of 16B
  {
    const unsigned char* xg = (const unsigned char*)xq;
#pragma unroll
    for (int j = 0; j < 2; ++j) {
      const int s = j * 256 + tid;            // row = s/8, 16B chunk = s%8
      g2lds8(xg + (rbase + (s >> 3)) * CD + (s & 7) * 16, &x8buf[(size_t)s * 16]);
    }
  }

  // batch ids for pooling (tiny)
  if (pooled && tid < GROWS) {
    size_t row = rbase + tid;
    sB[tid] = (row < NND) ? batch[row] : -1;
  }

  // B fragments -> registers (overlaps DMA; weights are L2-hot)
  s8v bL[2][4], bR[2][4];
#pragma unroll
  for (int nt = 0; nt < 2; ++nt) {
    const int n = wave * 32 + nt * 16 + l16;
#pragma unroll
    for (int kk = 0; kk < 4; ++kk) {
      size_t woff = (size_t)n * CD + kk * 32 + quad * 8;
      bL[nt][kk] = *reinterpret_cast<const s8v*>(WlT + woff);
      bR[nt][kk] = *reinterpret_cast<const s8v*>(WrT + woff);
    }
  }
  const float bv0 = bias[wave * 32 + l16];
  const float bv1 = bias[wave * 32 + 16 + l16];

  // Gather phase: 32 teams x 8 lanes; team handles rows rbase + team*2 + i
  {
    const int team = tid >> 3;
    const int tl   = tid & 7;                  // owns channels [tl*16, tl*16+16)
    const unsigned* base = xq + tl * 4;        // 4 u32 = 16 fp8 channels
    for (int i = 0; i < 2; ++i) {
      const int rl = team * 2 + i;
      const size_t row = rbase + rl;
      u16x8 o0 = {}, o1 = {};
      if (row < NND) {
        const int e0 = offs[row], e1 = offs[row + 1];
        f2v a[8] = {};
        int e = e0;
        for (; e + 4 <= e1; e += 4) {
          int s[4];
#pragma unroll
          for (int j = 0; j < 4; ++j) s[j] = csr[e + j];
          uint4 v[4];
#pragma unroll
          for (int j = 0; j < 4; ++j)
            v[j] = *reinterpret_cast<const uint4*>(base + (size_t)s[j] * 32);
#pragma unroll
          for (int j = 0; j < 4; ++j) {
            a[0] += __builtin_amdgcn_cvt_pk_f32_fp8(v[j].x, false);
            a[1] += __builtin_amdgcn_cvt_pk_f32_fp8(v[j].x, true);
            a[2] += __builtin_amdgcn_cvt_pk_f32_fp8(v[j].y, false);
            a[3] += __builtin_amdgcn_cvt_pk_f32_fp8(v[j].y, true);
            a[4] += __builtin_amdgcn_cvt_pk_f32_fp8(v[j].z, false);
            a[5] += __builtin_amdgcn_cvt_pk_f32_fp8(v[j].z, true);
            a[6] += __builtin_amdgcn_cvt_pk_f32_fp8(v[j].w, false);
            a[7] += __builtin_amdgcn_cvt_pk_f32_fp8(v[j].w, true);
          }
        }
        for (; e < e1; ++e) {
          uint4 v = *reinterpret_cast<const uint4*>(base + (size_t)csr[e] * 32);
          a[0] += __builtin_amdgcn_cvt_pk_f32_fp8(v.x, false);
          a[1] += __builtin_amdgcn_cvt_pk_f32_fp8(v.x, true);
          a[2] += __builtin_amdgcn_cvt_pk_f32_fp8(v.y, false);
          a[3] += __builtin_amdgcn_cvt_pk_f32_fp8(v.y, true);
          a[4] += __builtin_amdgcn_cvt_pk_f32_fp8(v.z, false);
          a[5] += __builtin_amdgcn_cvt_pk_f32_fp8(v.z, true);
          a[6] += __builtin_amdgcn_cvt_pk_f32_fp8(v.w, false);
          a[7] += __builtin_amdgcn_cvt_pk_f32_fp8(v.w, true);
        }
        const float invd = 1.0f / fmaxf((float)(e1 - e0), 1.0f);
#pragma unroll
        for (int c = 0; c < 4; ++c) {
          o0[2 * c]     = f2bf(a[c].x * invd);
          o0[2 * c + 1] = f2bf(a[c].y * invd);
          o1[2 * c]     = f2bf(a[4 + c].x * invd);
          o1[2 * c + 1] = f2bf(a[4 + c].y * invd);
        }
      }
      *reinterpret_cast<u16x8*>(abuf + rl * CD + tl * 16)     = o0;
      *reinterpret_cast<u16x8*>(abuf + rl * CD + tl * 16 + 8) = o1;
    }
  }

  __syncthreads();   // drains DMA (vmcnt) + LDS writes + barrier

  const bool fast = pooled && (rbase + GROWS <= NND) && (sB[0] == sB[GROWS - 1]);
  const int c0 = wave * 32 + l16;
  float p0 = 0.f, p1 = 0.f;

  // MFMA phase
#pragma unroll
  for (int rt = 0; rt < GROWS / 16; ++rt) {
    const unsigned short* arow = abuf + (rt * 16 + l16) * CD + quad * 8;
    const unsigned char*  xrow = x8buf + (rt * 16 + l16) * CD + quad * 8;
    f4v acc0 = {}, acc1 = {};
#pragma unroll
    for (int kk = 0; kk < 4; ++kk) {
      s8v aA = *reinterpret_cast<const s8v*>(arow + kk * 32);   // ds_read_b128
      s8v aX = fp8x8_to_bf16(*reinterpret_cast<const uint2*>(xrow + kk * 32));
      acc0 = __builtin_amdgcn_mfma_f32_16x16x32_bf16(aA, bL[0][kk], acc0, 0, 0, 0);
      acc0 = __builtin_amdgcn_mfma_f32_16x16x32_bf16(aX, bR[0][kk], acc0, 0, 0, 0);
      acc1 = __builtin_amdgcn_mfma_f32_16x16x32_bf16(aA, bL[1][kk], acc1, 0, 0, 0);
      acc1 = __builtin_amdgcn_mfma_f32_16x16x32_bf16(aX, bR[1][kk], acc1, 0, 0, 0);
    }
    const size_t row0 = rbase + rt * 16 + quad * 4;
#pragma unroll
    for (int r = 0; r < 4; ++r) {
      const size_t row = row0 + r;
      float v0 = fmaxf(acc0[r] + bv0, 0.0f);
      float v1 = fmaxf(acc1[r] + bv1, 0.0f);
      if (h8) {
        int q0 = __builtin_amdgcn_cvt_pk_fp8_f32(v0, v0, 0, false);
        int q1 = __builtin_amdgcn_cvt_pk_fp8_f32(v1, v1, 0, false);
        h8[row * CD + c0]      = (unsigned char)q0;
        h8[row * CD + c0 + 16] = (unsigned char)q1;
      }
      if (pooled) {
        if (fast) {
          p0 += v0; p1 += v1;
        } else {
          int g = sB[rt * 16 + quad * 4 + r];
          if (g >= 0) {
            atomicAdd(&pooled[g * CD + c0], v0);
            atomicAdd(&pooled[g * CD + c0 + 16], v1);
          }
        }
      }
    }
  }

  if (fast) {   // butterfly column-reduce across quads, one atomic pair per col
    p0 += __shfl_xor(p0, 16, 64);
    p0 += __shfl_xor(p0, 32, 64);
    p1 += __shfl_xor(p1, 16, 64);
    p1 += __shfl_xor(p1, 32, 64);
    if (quad == 0) {
      const int g = sB[0];
      atomicAdd(&pooled[g * CD + c0], p0);
      atomicAdd(&pooled[g * CD + c0 + 16], p1);
    }
  }
}

// ---- classifier: out[g] = sigmoid(dot(pooled[g]/cnt, Wc) + bc) ----
__global__ void final_k(const float* __restrict__ pooled, const int* __restrict__ gb,
                        const float* __restrict__ Wc, const float* __restrict__ bc,
                        float* __restrict__ out) {
  int g = blockIdx.x;
  int lane = threadIdx.x;
  float part = pooled[g * CD + lane] * Wc[lane] +
               pooled[g * CD + 64 + lane] * Wc[64 + lane];
#pragma unroll
  for (int off = 32; off > 0; off >>= 1) part += __shfl_down(part, off, 64);
  if (lane == 0) {
    float cnt = (float)(gb[g + 1] - gb[g]);
    float z = part / fmaxf(cnt, 1.0f) + bc[0];
    out[g] = 1.0f / (1.0f + expf(-z));
  }
}

extern "C" void kernel_launch(void* const* d_in, const int* in_sizes, int n_in,
                              void* d_out, int out_size, void* d_ws, size_t ws_size,
                              hipStream_t stream) {
  const float* x   = (const float*)d_in[0];
  const int*   ei  = (const int*)d_in[1];
  const int*   src = ei;             // edge_index[0]
  const int*   dst = ei + NED;       // edge_index[1]
  // d_in[2] = edge_weight: unused by the reference
  const int*   batch = (const int*)d_in[3];
  const float* Wc = (const float*)d_in[16];
  const float* bc = (const float*)d_in[17];
  float* out = (float*)d_out;

  char* w = (char*)d_ws;
  auto alloc = [&](size_t bytes) {
    char* p = w; w += (bytes + 255) & ~(size_t)255; return p;
  };
  // cnti + pooled first and contiguous: one memset covers both
  int* cnti = (int*)alloc(NND * 4);
  float* pooled = (float*)alloc(NG * CD * 4);
  size_t zspan = (size_t)(w - (char*)cnti);
  int* offs = (int*)alloc((NND + 1) * 4);
  int* cur  = (int*)alloc(NND * 4);
  int* csr  = (int*)alloc((size_t)NED * 4);
  int* gb   = (int*)alloc((NG + 1) * 4);
  int* bsum = (int*)alloc(256 * 4);
  int* boff = (int*)alloc(256 * 4);
  unsigned char* x8a = (unsigned char*)alloc((size_t)LNP * CD);
  unsigned char* x8b = (unsigned char*)alloc((size_t)LNP * CD);
  WPtrs wp;
  for (int i = 0; i < 4; ++i) {
    wp.w[2 * i]     = (const float*)d_in[4 + 3 * i];      // Wl{i+1}
    wp.w[2 * i + 1] = (const float*)d_in[5 + 3 * i];      // Wr{i+1}
  }
  for (int i = 0; i < 8; ++i) wp.wt[i] = (unsigned short*)alloc(CD * CD * 2);
  const float* bs[4] = {(const float*)d_in[6],  (const float*)d_in[9],
                        (const float*)d_in[12], (const float*)d_in[15]};

  hipMemsetAsync(cnti, 0, zspan, stream);

  // preamble: fp8 convert + weight transposes + degree count in ONE kernel
  prep_k<<<(NND * 32 + 8 * CD * CD + NED + 255) / 256, 256, 0, stream>>>(
      x, (unsigned*)x8a, wp, dst, cnti);

  // CSR build (per call; inputs are restored before every timed launch)
  bsum_k<<<NBLK, 256, 0, stream>>>(cnti, bsum);
  bscan_k<<<1, 256, 0, stream>>>(bsum, boff, offs, batch, gb);
  escan_k<<<NBLK, 256, 0, stream>>>(cnti, boff, offs, cur);
  fill_k<<<(NED + 255) / 256, 256, 0, stream>>>(src, dst, cur, csr);

  unsigned char* qcur = x8a;
  unsigned char* qnxt = x8b;
  const int ggrid = LNP / GROWS;   // 782, guard-free
  for (int l = 0; l < 4; ++l) {
    if (l < 3) {
      sage_k<<<ggrid, 256, 0, stream>>>((const unsigned*)qcur, csr, offs,
                                        wp.wt[2 * l], wp.wt[2 * l + 1], bs[l],
                                        qnxt, batch, nullptr);
      unsigned char* q = qcur; qcur = qnxt; qnxt = q;
    } else {
      // last layer: no feature output — pooling fused into epilogue
      sage_k<<<ggrid, 256, 0, stream>>>((const unsigned*)qcur, csr, offs,
                                        wp.wt[2 * l], wp.wt[2 * l + 1], bs[l],
                                        nullptr, batch, pooled);
    }
  }

  final_k<<<NG, 64, 0, stream>>>(pooled, gb, Wc, bc, out);
}